// Round 1
// baseline (808.967 us; speedup 1.0000x reference)
//
#include <hip/hip_runtime.h>
#include <cstdint>

#define E_TOTAL 320000
#define NN 10000
#define DIN 256
#define HDIM 512
#define DOUT 256
#define M_TILE 48
#define N_MAIN_BLOCKS ((E_TOTAL + M_TILE - 1) / M_TILE)  // 6667

typedef __attribute__((ext_vector_type(8))) short short8;
typedef __attribute__((ext_vector_type(4))) float f32x4;

__device__ __forceinline__ unsigned short f2bf(float f) {
    union { float f; unsigned u; } v; v.f = f;
    unsigned u = v.u;
    return (unsigned short)((u + 0x7fffu + ((u >> 16) & 1u)) >> 16);  // RNE
}

// ---- detect whether edge_index arrived as int64 (high dwords all zero) ----
__global__ void detect_i64(const int* __restrict__ eidx, int* __restrict__ flag) {
    __shared__ int anynz;
    if (threadIdx.x == 0) anynz = 0;
    __syncthreads();
    int v = 0;
    for (int i = threadIdx.x; i < 8192; i += blockDim.x) v |= eidx[2 * i + 1];
    if (v != 0) atomicOr(&anynz, 1);
    __syncthreads();
    if (threadIdx.x == 0) *flag = (anynz == 0) ? 1 : 0;
}

// ---- x fp32 -> bf16 ----
__global__ void convert_x(const float* __restrict__ x, unsigned short* __restrict__ xb) {
    int total = NN * DIN;
    for (int i = blockIdx.x * blockDim.x + threadIdx.x; i < total; i += gridDim.x * blockDim.x)
        xb[i] = f2bf(x[i]);
}

// ---- pack W (row-major [K][ncols] fp32) into per-(coltile,kstep) B-fragment
// layout for mfma_f32_16x16x32_bf16: lane l holds B[k=(l>>4)*8+j][n=l&15]. ----
__global__ void pack_w(const float* __restrict__ W, unsigned short* __restrict__ Wp,
                       int ncols, int nct, int nks) {
    int tid = blockIdx.x * blockDim.x + threadIdx.x;
    int total = nct * nks * 64;
    if (tid >= total) return;
    int lane = tid & 63;
    int ks = (tid >> 6) % nks;
    int ct = tid / (64 * nks);
    int k0 = ks * 32 + (lane >> 4) * 8;
    int n = ct * 16 + (lane & 15);
    short8 v;
#pragma unroll
    for (int j = 0; j < 8; j++) v[j] = (short)f2bf(W[(long)(k0 + j) * ncols + n]);
    *(short8*)(Wp + ((long)(ct * nks + ks) * 64 + lane) * 8) = v;
}

// ---- fused edge MLP ----
// block = 256 threads (4 waves), M_TILE=48 edges, out tile 48x256 in regs.
// LDS: ef[48][512] bf16 (XOR-swizzled 16B chunks), hb[48][128] bf16 chunk buffer.
__global__ __launch_bounds__(256, 2)
void edge_mlp(const unsigned short* __restrict__ xb,
              const int* __restrict__ eidx,
              const float* __restrict__ b1,
              const unsigned short* __restrict__ W1p,
              const float* __restrict__ b2v_g,
              const unsigned short* __restrict__ W2p,
              const int* __restrict__ flag,
              float* __restrict__ out)
{
    __shared__ unsigned short ef[M_TILE * 512];  // 49152 B
    __shared__ unsigned short hb[M_TILE * 128];  // 12288 B

    const int tid = threadIdx.x;
    const int lane = tid & 63;
    const int w = tid >> 6;
    const int lo = lane & 15;
    const int quad = lane >> 4;
    const long e0 = (long)blockIdx.x * M_TILE;
    const bool is64 = (*flag != 0);

    // ---- stage ef via global_load_lds (1 KiB row per instruction) ----
    // LDS chunk p of row r holds logical chunk p^(r&7); logical chunks 0..31 =
    // start-node row, 32..63 = end-node row.
#pragma unroll
    for (int i = 0; i < 12; i++) {
        int r = i * 4 + w;                    // wave-uniform row
        long e = e0 + r;
        long ec = (e < E_TOTAL) ? e : 0;
        long sn, tn;
        if (is64) {
            sn = ((const long long*)eidx)[ec];
            tn = ((const long long*)eidx)[E_TOTAL + ec];
        } else {
            sn = eidx[ec];
            tn = eidx[E_TOTAL + ec];
        }
        long node = (lane < 32) ? sn : tn;
        int cih = (lane & 31) ^ (r & 7);      // source chunk within half (XOR swizzle)
        const unsigned short* g = xb + node * DIN + cih * 8;
        unsigned roff = __builtin_amdgcn_readfirstlane((unsigned)(r * 512));
        __builtin_amdgcn_global_load_lds(
            (const __attribute__((address_space(1))) void*)g,
            (__attribute__((address_space(3))) void*)(ef + roff),
            16, 0, 0);
    }
    __syncthreads();

    f32x4 oacc[3][4];
#pragma unroll
    for (int rt = 0; rt < 3; rt++)
#pragma unroll
        for (int ct = 0; ct < 4; ct++)
            oacc[rt][ct] = (f32x4){0.f, 0.f, 0.f, 0.f};

    for (int kc = 0; kc < 4; kc++) {
        // ---- GEMM1: h chunk [48 x 128]; this wave computes cols w*32..w*32+31 ----
        f32x4 hacc[3][2];
#pragma unroll
        for (int rt = 0; rt < 3; rt++)
#pragma unroll
            for (int ct = 0; ct < 2; ct++)
                hacc[rt][ct] = (f32x4){0.f, 0.f, 0.f, 0.f};

#pragma unroll 4
        for (int ks = 0; ks < 16; ks++) {
            short8 a[3];
#pragma unroll
            for (int rt = 0; rt < 3; rt++) {
                int m = rt * 16 + lo;
                int c = (ks * 4 + quad) ^ (m & 7);
                a[rt] = *(const short8*)(ef + m * 512 + c * 8);
            }
#pragma unroll
            for (int ct = 0; ct < 2; ct++) {
                int ctg = kc * 8 + w * 2 + ct;
                short8 bfr = *(const short8*)(W1p + ((long)(ctg * 16 + ks) * 64 + lane) * 8);
#pragma unroll
                for (int rt = 0; rt < 3; rt++)
                    hacc[rt][ct] = __builtin_amdgcn_mfma_f32_16x16x32_bf16(
                        a[rt], bfr, hacc[rt][ct], 0, 0, 0);
            }
        }

        // ---- bias + relu + bf16 -> hb (C-layout -> swizzled row-major) ----
#pragma unroll
        for (int ct = 0; ct < 2; ct++) {
            int cwl = w * 32 + ct * 16 + lo;        // col within chunk (0..127)
            float bias = b1[kc * 128 + cwl];
            int c = cwl >> 3;
            int cb = cwl & 7;
#pragma unroll
            for (int rt = 0; rt < 3; rt++) {
#pragma unroll
                for (int rr = 0; rr < 4; rr++) {
                    int rw = rt * 16 + quad * 4 + rr;
                    float v = fmaxf(hacc[rt][ct][rr] + bias, 0.f);
                    hb[rw * 128 + ((c ^ (rw & 7)) << 3) + cb] = f2bf(v);
                }
            }
        }
        __syncthreads();

        // ---- GEMM2: out[48x256] += h_chunk @ W2[kc*128.., :]; wave cols w*64.. ----
#pragma unroll
        for (int s = 0; s < 4; s++) {
            short8 a2[3];
#pragma unroll
            for (int rt = 0; rt < 3; rt++) {
                int m = rt * 16 + lo;
                int c = (s * 4 + quad) ^ (m & 7);
                a2[rt] = *(const short8*)(hb + m * 128 + c * 8);
            }
#pragma unroll
            for (int ct = 0; ct < 4; ct++) {
                int ctg = w * 4 + ct;
                int ks2 = kc * 4 + s;
                short8 bfr = *(const short8*)(W2p + ((long)(ctg * 16 + ks2) * 64 + lane) * 8);
#pragma unroll
                for (int rt = 0; rt < 3; rt++)
                    oacc[rt][ct] = __builtin_amdgcn_mfma_f32_16x16x32_bf16(
                        a2[rt], bfr, oacc[rt][ct], 0, 0, 0);
            }
        }
        __syncthreads();
    }

    // ---- epilogue: +b2, store fp32 ----
    float bv[4];
#pragma unroll
    for (int ct = 0; ct < 4; ct++) bv[ct] = b2v_g[w * 64 + ct * 16 + lo];
#pragma unroll
    for (int rt = 0; rt < 3; rt++) {
#pragma unroll
        for (int rr = 0; rr < 4; rr++) {
            int rw = rt * 16 + quad * 4 + rr;
            long e = e0 + rw;
            if (e < E_TOTAL) {
                float* op = out + e * DOUT + w * 64 + lo;
#pragma unroll
                for (int ct = 0; ct < 4; ct++)
                    op[ct * 16] = oacc[rt][ct][rr] + bv[ct];
            }
        }
    }
}

extern "C" void kernel_launch(void* const* d_in, const int* in_sizes, int n_in,
                              void* d_out, int out_size, void* d_ws, size_t ws_size,
                              hipStream_t stream) {
    const float* x   = (const float*)d_in[0];
    const int*   ei  = (const int*)d_in[1];
    const float* W1  = (const float*)d_in[2];
    const float* b1  = (const float*)d_in[3];
    const float* W2  = (const float*)d_in[4];
    const float* b2  = (const float*)d_in[5];
    float* out = (float*)d_out;

    // workspace layout (bytes): xb 5,120,000 | W1p 524,288 | W2p 262,144 | flag 4
    unsigned short* xb  = (unsigned short*)d_ws;
    unsigned short* W1p = (unsigned short*)((char*)d_ws + 5120000);
    unsigned short* W2p = (unsigned short*)((char*)d_ws + 5644288);
    int* flag = (int*)((char*)d_ws + 5906432);

    hipLaunchKernelGGL(detect_i64, dim3(1), dim3(256), 0, stream, ei, flag);
    hipLaunchKernelGGL(convert_x, dim3(1024), dim3(256), 0, stream, x, xb);
    hipLaunchKernelGGL(pack_w, dim3(128), dim3(256), 0, stream, W1, W1p, HDIM, 32, 16);
    hipLaunchKernelGGL(pack_w, dim3(64), dim3(256), 0, stream, W2, W2p, DOUT, 16, 16);
    hipLaunchKernelGGL(edge_mlp, dim3(N_MAIN_BLOCKS), dim3(256), 0, stream,
                       xb, ei, b1, W1p, b2, W2p, flag, out);
}

// Round 2
// 688.136 us; speedup vs baseline: 1.1756x; 1.1756x over previous
//
#include <hip/hip_runtime.h>
#include <cstdint>

#define E_TOTAL 320000
#define NN 10000
#define DIN 256
#define HDIM 512
#define DOUT 256
#define M_TILE 48
#define N_MAIN_BLOCKS ((E_TOTAL + M_TILE - 1) / M_TILE)  // 6667

typedef __attribute__((ext_vector_type(8))) short short8;
typedef __attribute__((ext_vector_type(4))) float f32x4;

__device__ __forceinline__ unsigned short f2bf(float f) {
    union { float f; unsigned u; } v; v.f = f;
    unsigned u = v.u;
    return (unsigned short)((u + 0x7fffu + ((u >> 16) & 1u)) >> 16);  // RNE
}

// ---- detect whether edge_index arrived as int64 (high dwords all zero) ----
__global__ void detect_i64(const int* __restrict__ eidx, int* __restrict__ flag) {
    __shared__ int anynz;
    if (threadIdx.x == 0) anynz = 0;
    __syncthreads();
    int v = 0;
    for (int i = threadIdx.x; i < 8192; i += blockDim.x) v |= eidx[2 * i + 1];
    if (v != 0) atomicOr(&anynz, 1);
    __syncthreads();
    if (threadIdx.x == 0) *flag = (anynz == 0) ? 1 : 0;
}

// ---- x fp32 -> bf16 ----
__global__ void convert_x(const float* __restrict__ x, unsigned short* __restrict__ xb) {
    int total = NN * DIN;
    for (int i = blockIdx.x * blockDim.x + threadIdx.x; i < total; i += gridDim.x * blockDim.x)
        xb[i] = f2bf(x[i]);
}

// ---- pack W (row-major [K][ncols] fp32) into per-(coltile,kstep) B-fragment
// layout for mfma_f32_16x16x32_bf16: lane l holds B[k=(l>>4)*8+j][n=l&15]. ----
__global__ void pack_w(const float* __restrict__ W, unsigned short* __restrict__ Wp,
                       int ncols, int nct, int nks) {
    int tid = blockIdx.x * blockDim.x + threadIdx.x;
    int total = nct * nks * 64;
    if (tid >= total) return;
    int lane = tid & 63;
    int ks = (tid >> 6) % nks;
    int ct = tid / (64 * nks);
    int k0 = ks * 32 + (lane >> 4) * 8;
    int n = ct * 16 + (lane & 15);
    short8 v;
#pragma unroll
    for (int j = 0; j < 8; j++) v[j] = (short)f2bf(W[(long)(k0 + j) * ncols + n]);
    *(short8*)(Wp + ((long)(ct * nks + ks) * 64 + lane) * 8) = v;
}

// ---- fused edge MLP ----
// block = 256 threads (4 waves), M_TILE=48 edges, out tile 48x256 in regs.
// LDS: ef[48][512] bf16 (XOR-swizzled 16B chunks), hb[48][128] bf16 chunk buffer.
// LDS caps occupancy at 2 blocks/CU (8 waves) -> VGPRs up to 256 are free;
// spend them on deep register prefetch of W-fragments to hide L2/L3 latency.
__global__ __launch_bounds__(256, 2)
void edge_mlp(const unsigned short* __restrict__ xb,
              const int* __restrict__ eidx,
              const float* __restrict__ b1,
              const unsigned short* __restrict__ W1p,
              const float* __restrict__ b2v_g,
              const unsigned short* __restrict__ W2p,
              const int* __restrict__ flag,
              float* __restrict__ out)
{
    __shared__ unsigned short ef[M_TILE * 512];  // 49152 B
    __shared__ unsigned short hb[M_TILE * 128];  // 12288 B

    const int tid = threadIdx.x;
    const int lane = tid & 63;
    const int w = tid >> 6;
    const int lo = lane & 15;
    const int quad = lane >> 4;
    const long e0 = (long)blockIdx.x * M_TILE;
    const bool is64 = (*flag != 0);

    // ---- stage ef via global_load_lds (1 KiB row per instruction) ----
#pragma unroll
    for (int i = 0; i < 12; i++) {
        int r = i * 4 + w;                    // wave-uniform row
        long e = e0 + r;
        long ec = (e < E_TOTAL) ? e : 0;
        long sn, tn;
        if (is64) {
            sn = ((const long long*)eidx)[ec];
            tn = ((const long long*)eidx)[E_TOTAL + ec];
        } else {
            sn = eidx[ec];
            tn = eidx[E_TOTAL + ec];
        }
        long node = (lane < 32) ? sn : tn;
        int cih = (lane & 31) ^ (r & 7);      // source chunk within half (XOR swizzle)
        const unsigned short* g = xb + node * DIN + cih * 8;
        unsigned roff = __builtin_amdgcn_readfirstlane((unsigned)(r * 512));
        __builtin_amdgcn_global_load_lds(
            (const __attribute__((address_space(1))) void*)g,
            (__attribute__((address_space(3))) void*)(ef + roff),
            16, 0, 0);
    }
    __syncthreads();

    f32x4 oacc[3][4];
#pragma unroll
    for (int rt = 0; rt < 3; rt++)
#pragma unroll
        for (int ct = 0; ct < 4; ct++)
            oacc[rt][ct] = (f32x4){0.f, 0.f, 0.f, 0.f};

    auto loadA1 = [&](short8* dst, int ks) {
#pragma unroll
        for (int rt = 0; rt < 3; rt++) {
            int m = rt * 16 + lo;
            int c = (ks * 4 + quad) ^ (m & 7);
            dst[rt] = *(const short8*)(ef + m * 512 + c * 8);
        }
    };

    for (int kc = 0; kc < 4; kc++) {
        // ---- preload ALL W2 frags for this kc (hidden behind GEMM1) ----
        short8 w2f[16];
#pragma unroll
        for (int s = 0; s < 4; s++)
#pragma unroll
            for (int ct = 0; ct < 4; ct++) {
                int ctg = w * 4 + ct;
                int ks2 = kc * 4 + s;
                w2f[s * 4 + ct] =
                    *(const short8*)(W2p + ((long)(ctg * 16 + ks2) * 64 + lane) * 8);
            }
        // preload biases for this kc
        float b1v[2];
#pragma unroll
        for (int ct = 0; ct < 2; ct++) b1v[ct] = b1[kc * 128 + w * 32 + ct * 16 + lo];

        // ---- GEMM1: h chunk [48 x 128]; this wave computes cols w*32..w*32+31 ----
        f32x4 hacc[3][2];
#pragma unroll
        for (int rt = 0; rt < 3; rt++)
#pragma unroll
            for (int ct = 0; ct < 2; ct++)
                hacc[rt][ct] = (f32x4){0.f, 0.f, 0.f, 0.f};

        short8 a_p[2][3], b_p[2][2];
        loadA1(a_p[0], 0);
#pragma unroll
        for (int ct = 0; ct < 2; ct++) {
            int ctg = kc * 8 + w * 2 + ct;
            b_p[0][ct] = *(const short8*)(W1p + ((long)(ctg * 16 + 0) * 64 + lane) * 8);
        }

#pragma unroll
        for (int ks = 0; ks < 16; ks++) {
            int cur = ks & 1, nxt = cur ^ 1;
            if (ks < 15) {
                loadA1(a_p[nxt], ks + 1);
#pragma unroll
                for (int ct = 0; ct < 2; ct++) {
                    int ctg = kc * 8 + w * 2 + ct;
                    b_p[nxt][ct] =
                        *(const short8*)(W1p + ((long)(ctg * 16 + ks + 1) * 64 + lane) * 8);
                }
            }
#pragma unroll
            for (int ct = 0; ct < 2; ct++)
#pragma unroll
                for (int rt = 0; rt < 3; rt++)
                    hacc[rt][ct] = __builtin_amdgcn_mfma_f32_16x16x32_bf16(
                        a_p[cur][rt], b_p[cur][ct], hacc[rt][ct], 0, 0, 0);
        }

        // ---- bias + relu + bf16 -> hb (C-layout -> swizzled row-major) ----
#pragma unroll
        for (int ct = 0; ct < 2; ct++) {
            int cwl = w * 32 + ct * 16 + lo;        // col within chunk (0..127)
            float bias = b1v[ct];
            int c = cwl >> 3;
            int cb = cwl & 7;
#pragma unroll
            for (int rt = 0; rt < 3; rt++) {
#pragma unroll
                for (int rr = 0; rr < 4; rr++) {
                    int rw = rt * 16 + quad * 4 + rr;
                    float v = fmaxf(hacc[rt][ct][rr] + bias, 0.f);
                    hb[rw * 128 + ((c ^ (rw & 7)) << 3) + cb] = f2bf(v);
                }
            }
        }
        __syncthreads();

        // ---- GEMM2: out[48x256] += h_chunk @ W2[kc*128.., :]; wave cols w*64.. ----
        short8 a2_p[2][3];
#pragma unroll
        for (int rt = 0; rt < 3; rt++) {
            int m = rt * 16 + lo;
            int c = (0 + quad) ^ (m & 7);
            a2_p[0][rt] = *(const short8*)(hb + m * 128 + c * 8);
        }
#pragma unroll
        for (int s = 0; s < 4; s++) {
            int cur = s & 1, nxt = cur ^ 1;
            if (s < 3) {
#pragma unroll
                for (int rt = 0; rt < 3; rt++) {
                    int m = rt * 16 + lo;
                    int c = ((s + 1) * 4 + quad) ^ (m & 7);
                    a2_p[nxt][rt] = *(const short8*)(hb + m * 128 + c * 8);
                }
            }
#pragma unroll
            for (int ct = 0; ct < 4; ct++)
#pragma unroll
                for (int rt = 0; rt < 3; rt++)
                    oacc[rt][ct] = __builtin_amdgcn_mfma_f32_16x16x32_bf16(
                        a2_p[cur][rt], w2f[s * 4 + ct], oacc[rt][ct], 0, 0, 0);
        }
        if (kc < 3) __syncthreads();   // protect hb rewrite; skip after last chunk
    }

    // ---- epilogue: +b2, store fp32 ----
    float bv[4];
#pragma unroll
    for (int ct = 0; ct < 4; ct++) bv[ct] = b2v_g[w * 64 + ct * 16 + lo];
#pragma unroll
    for (int rt = 0; rt < 3; rt++) {
#pragma unroll
        for (int rr = 0; rr < 4; rr++) {
            int rw = rt * 16 + quad * 4 + rr;
            long e = e0 + rw;
            if (e < E_TOTAL) {
                float* op = out + e * DOUT + w * 64 + lo;
#pragma unroll
                for (int ct = 0; ct < 4; ct++)
                    op[ct * 16] = oacc[rt][ct][rr] + bv[ct];
            }
        }
    }
}

extern "C" void kernel_launch(void* const* d_in, const int* in_sizes, int n_in,
                              void* d_out, int out_size, void* d_ws, size_t ws_size,
                              hipStream_t stream) {
    const float* x   = (const float*)d_in[0];
    const int*   ei  = (const int*)d_in[1];
    const float* W1  = (const float*)d_in[2];
    const float* b1  = (const float*)d_in[3];
    const float* W2  = (const float*)d_in[4];
    const float* b2  = (const float*)d_in[5];
    float* out = (float*)d_out;

    // workspace layout (bytes): xb 5,120,000 | W1p 524,288 | W2p 262,144 | flag 4
    unsigned short* xb  = (unsigned short*)d_ws;
    unsigned short* W1p = (unsigned short*)((char*)d_ws + 5120000);
    unsigned short* W2p = (unsigned short*)((char*)d_ws + 5644288);
    int* flag = (int*)((char*)d_ws + 5906432);

    hipLaunchKernelGGL(detect_i64, dim3(1), dim3(256), 0, stream, ei, flag);
    hipLaunchKernelGGL(convert_x, dim3(1024), dim3(256), 0, stream, x, xb);
    hipLaunchKernelGGL(pack_w, dim3(128), dim3(256), 0, stream, W1, W1p, HDIM, 32, 16);
    hipLaunchKernelGGL(pack_w, dim3(64), dim3(256), 0, stream, W2, W2p, DOUT, 16, 16);
    hipLaunchKernelGGL(edge_mlp, dim3(N_MAIN_BLOCKS), dim3(256), 0, stream,
                       xb, ei, b1, W1p, b2, W2p, flag, out);
}